// Round 12
// baseline (36.431 us; speedup 1.0000x reference)
//
#include <hip/hip_runtime.h>
#include <math.h>

#define N_HALF 4096
#define D 64
#define M_TOT 8192
#define NPAIR 2080   // 64*65/2 upper-triangle 128x128 tile pairs
#define NBLK 1040    // 2 pairs per block

typedef _Float16 half8 __attribute__((ext_vector_type(8)));
typedef float f32x4 __attribute__((ext_vector_type(4)));

// Device-global scratch (fully rewritten by plain stores every call).
// R9 lesson: no per-block device fences / ticket counters (XCD-L2 writeback
// serializes the machine). Cross-kernel deps via separate dispatches only.
__device__ _Float16 Fh[M_TOT * D];  // 1 MB fragment-major fp16 data
__device__ float g_norms[M_TOT];    // exact fp32 row norms
__device__ float g_pssq[256];       // per-prep-block sum-of-squares partials
__device__ float g_pcol[256 * D];   // per-prep-block column-sum partials
__device__ double g_part[NBLK];     // per-block signed partial sums

// Prep: fp16 convert into MFMA fragment-major layout + exact fp32 row norms
// + block partials for the bandwidth. F[rt][s][lane][e] =
// X[rt*16 + (lane&15)][s*32 + (lane>>4)*8 + e]  (same bijection for A and B
// operands -> dot products correct for any intra-MFMA k-order).
__global__ __launch_bounds__(256) void mmd_prep(const float* __restrict__ src,
                                                const float* __restrict__ tgt) {
    __shared__ float cs[D];
    __shared__ float hn[4][16];
    int t = threadIdx.x;
    if (t < D) cs[t] = 0.f;
    __syncthreads();
    int tid = blockIdx.x * 256 + t;  // 65536 threads total
    int l = tid & 63;
    int rs = tid >> 6;
    int s = rs & 1, rt = rs >> 1;
    int row = rt * 16 + (l & 15);
    int k0 = s * 32 + (l >> 4) * 8;
    const float* X = (row < N_HALF) ? src + (size_t)row * D
                                    : tgt + (size_t)(row - N_HALF) * D;
    float4 v0 = ((const float4*)(X + k0))[0];
    float4 v1 = ((const float4*)(X + k0))[1];
    float vs[8] = {v0.x, v0.y, v0.z, v0.w, v1.x, v1.y, v1.z, v1.w};
    half8 h;
    float p = 0.f;
#pragma unroll
    for (int e = 0; e < 8; ++e) {
        h[e] = (_Float16)vs[e];  // RNE
        p += vs[e] * vs[e];
    }
    ((half8*)Fh)[tid] = h;
#pragma unroll
    for (int e = 0; e < 8; ++e) atomicAdd(&cs[k0 + e], vs[e]);  // LDS only
    // lanes l, l+16, l+32, l+48 share (row, s-half)
    p += __shfl_down(p, 32, 64);
    p += __shfl_down(p, 16, 64);
    int w = t >> 6;
    if (l < 16) hn[w][l] = p;
    __syncthreads();
    if (t < 64) {
        float nr = 0.f;
        int tile = t >> 4, r = t & 15;
        if (t < 32) {
            nr = hn[tile * 2][r] + hn[tile * 2 + 1][r];
            g_norms[(blockIdx.x * 2 + tile) * 16 + r] = nr;
        }
        nr += __shfl_down(nr, 32, 64);
        nr += __shfl_down(nr, 16, 64);
        nr += __shfl_down(nr, 8, 64);
        nr += __shfl_down(nr, 4, 64);
        nr += __shfl_down(nr, 2, 64);
        nr += __shfl_down(nr, 1, 64);
        if (t == 0) g_pssq[blockIdx.x] = nr;
    }
    if (t < D) g_pcol[blockIdx.x * D + t] = cs[t];
}

static __device__ inline void decode_pair(int id, int& bi, int& bj) {
    bi = (int)(64.5f - sqrtf(4160.25f - 2.0f * (float)id));
    while ((64 * (bi + 1) - ((bi + 1) * bi) / 2) <= id) ++bi;
    while ((64 * bi - (bi * (bi - 1)) / 2) > id) --bi;
    bj = bi + (id - (64 * bi - (bi * (bi - 1)) / 2));
}

// Main: TWO 128x128 pair tiles per block (1040 blocks), 8 waves of 64x32.
// Per-block wave-striped bandwidth preamble (overlaps fragment loads; g0 is
// only needed at the epilogue). Sign applied lane-locally; ONE block reduce.
__global__ __launch_bounds__(512) void mmd_main() {
    __shared__ float scol[8][64];
    __shared__ float sssq[8];
    __shared__ float sred[8];
    int t = threadIdx.x, w = t >> 6, l = t & 63;
    int wr = w >> 2, wc = w & 3;  // 2x4 wave grid: 64 rows x 32 cols per wave
    const half8* FH = (const half8*)Fh;

    // --- bandwidth preamble: 256 prep-partials striped over 8 waves ---
    {
        float csum = 0.f;
#pragma unroll 8
        for (int q = 0; q < 32; ++q) csum += g_pcol[((w * 32 + q) << 6) + l];
        float sq = (l < 32) ? g_pssq[w * 32 + l] : 0.f;
#pragma unroll
        for (int off = 32; off; off >>= 1) sq += __shfl_xor(sq, off, 64);
        scol[w][l] = csum;
        if (l == 0) sssq[w] = sq;
    }
    __syncthreads();
    float g0, c2;
    {
        float colsum = ((scol[0][l] + scol[1][l]) + (scol[2][l] + scol[3][l])) +
                       ((scol[4][l] + scol[5][l]) + (scol[6][l] + scol[7][l]));
        float s2 = colsum * colsum;
#pragma unroll
        for (int off = 32; off; off >>= 1) s2 += __shfl_xor(s2, off, 64);
        float ssq = ((sssq[0] + sssq[1]) + (sssq[2] + sssq[3])) +
                    ((sssq[4] + sssq[5]) + (sssq[6] + sssq[7]));
        const float M = (float)M_TOT;
        float sumL2 = 2.f * M * ssq - 2.f * s2;
        float bwq = sumL2 / (M * M - M) * 0.25f;  // / KERNEL_MUL^(KERNEL_NUM//2)
        g0 = -1.4426950408889634f / (bwq * 16.f);
        c2 = -2.f * g0;
    }

    float mypart = 0.f;
#pragma unroll
    for (int p = 0; p < 2; ++p) {
        int id = blockIdx.x * 2 + p;
        int bi, bj;
        decode_pair(id, bi, bj);

        // Norm loads issued early (consumed in epilogue).
        float nas[4][4];
#pragma unroll
        for (int m = 0; m < 4; ++m) {
            float4 v = *(const float4*)&g_norms[bi * 128 + wr * 64 + m * 16 + (l >> 4) * 4];
            nas[m][0] = v.x; nas[m][1] = v.y; nas[m][2] = v.z; nas[m][3] = v.w;
        }
        float nbv[2];
#pragma unroll
        for (int n = 0; n < 2; ++n)
            nbv[n] = g_norms[bj * 128 + wc * 32 + n * 16 + (l & 15)];

        f32x4 acc[4][2] = {};
#pragma unroll
        for (int s = 0; s < 2; ++s) {
            half8 bh[2];
#pragma unroll
            for (int n = 0; n < 2; ++n)
                bh[n] = FH[((bj * 8 + wc * 2 + n) * 2 + s) * 64 + l];
#pragma unroll
            for (int m = 0; m < 4; ++m) {
                half8 ah = FH[((bi * 8 + wr * 4 + m) * 2 + s) * 64 + l];
#pragma unroll
                for (int n = 0; n < 2; ++n)
                    acc[m][n] = __builtin_amdgcn_mfma_f32_16x16x32_f16(ah, bh[n], acc[m][n], 0, 0, 0);
            }
        }

        // Epilogue: K_sum over 5 bandwidths via 1 exp2 + 4 squarings.
        float part4[4] = {0.f, 0.f, 0.f, 0.f};
#pragma unroll
        for (int m = 0; m < 4; ++m)
#pragma unroll
            for (int n = 0; n < 2; ++n)
#pragma unroll
                for (int r = 0; r < 4; ++r) {
                    float t0 = fmaf(acc[m][n][r], c2, (nas[m][r] + nbv[n]) * g0);
                    float k4 = __builtin_amdgcn_exp2f(t0);
                    float k3 = k4 * k4;
                    float k2 = k3 * k3;
                    float k1 = k2 * k2;
                    float k0 = k1 * k1;
                    part4[r] += (k4 + k3) + ((k2 + k1) + k0);
                }
        float part = (part4[0] + part4[1]) + (part4[2] + part4[3]);
        float sgn = ((bi < 32) == (bj < 32)) ? 1.f : -1.f;
        float scl = (bi == bj) ? 1.f : 2.f;
        mypart = fmaf(part, sgn * scl, mypart);
    }

    // One block reduce for both pairs (sign already applied lane-locally).
#pragma unroll
    for (int off = 32; off; off >>= 1) mypart += __shfl_down(mypart, off, 64);
    if (l == 0) sred[w] = mypart;
    __syncthreads();
    if (t == 0) {
        float tot = ((sred[0] + sred[1]) + (sred[2] + sred[3])) +
                    ((sred[4] + sred[5]) + (sred[6] + sred[7]));
        g_part[blockIdx.x] = (double)tot;
    }
}

// Deterministic tree reduce of the 1040 per-block doubles.
__global__ __launch_bounds__(256) void mmd_out(float* __restrict__ out) {
    __shared__ double wred[4];
    int t = threadIdx.x;
    double s = 0.0;
    for (int i = t; i < NBLK; i += 256) s += g_part[i];
#pragma unroll
    for (int off = 32; off; off >>= 1) s += __shfl_down(s, off, 64);
    if ((t & 63) == 0) wred[t >> 6] = s;
    __syncthreads();
    if (t == 0)
        out[0] = (float)((wred[0] + wred[1] + wred[2] + wred[3]) * (1.0 / 16777216.0));
}

extern "C" void kernel_launch(void* const* d_in, const int* in_sizes, int n_in,
                              void* d_out, int out_size, void* d_ws, size_t ws_size,
                              hipStream_t stream) {
    const float* src = (const float*)d_in[0];
    const float* tgt = (const float*)d_in[1];
    float* out = (float*)d_out;

    mmd_prep<<<256, 256, 0, stream>>>(src, tgt);
    mmd_main<<<NBLK, 512, 0, stream>>>();
    mmd_out<<<1, 256, 0, stream>>>(out);
}

// Round 14
// 33.613 us; speedup vs baseline: 1.0838x; 1.0838x over previous
//
#include <hip/hip_runtime.h>
#include <math.h>

#define N_HALF 4096
#define D 64
#define M_TOT 8192
#define NPAIR 2080  // 64*65/2 upper-triangle 128x128 tile pairs

typedef _Float16 half8 __attribute__((ext_vector_type(8)));
typedef float f32x4 __attribute__((ext_vector_type(4)));

// Device-global scratch (fully rewritten by plain stores every call).
// R9 lesson: no per-block device fences / ticket counters.
__device__ _Float16 Fh[M_TOT * D];  // 1 MB fragment-major fp16 data
__device__ float g_norms[M_TOT];    // exact fp32 row norms
__device__ float g_pssq[256];       // per-prep-block sum-of-squares partials
__device__ float g_pcol[256 * D];   // per-prep-block column-sum partials
__device__ float g_coef;            // base exp2 coefficient g0
__device__ double g_part[NPAIR];    // per-pair signed partial sums

// Prep: fp16 convert into MFMA fragment-major layout + exact fp32 row norms
// + block partials for the bandwidth. Colsum partials via wave shuffles.
// NOTE: wave w covers k-half s = w&1 only -> cs[w] has valid data ONLY in
// columns [s*32, s*32+32); the combine below must select, not sum-all (R13 bug).
// F[rt][s][lane][e] = X[rt*16 + (lane&15)][s*32 + (lane>>4)*8 + e]
__global__ __launch_bounds__(256) void mmd_prep(const float* __restrict__ src,
                                                const float* __restrict__ tgt) {
    __shared__ float cs[4][D];  // per-wave column partials (half-valid each)
    __shared__ float hn[4][16];
    int t = threadIdx.x;
    int tid = blockIdx.x * 256 + t;  // 65536 threads total
    int l = t & 63;
    int rs = tid >> 6;
    int s = rs & 1, rt = rs >> 1;    // uniform per wave; s == (t>>6)&1
    int row = rt * 16 + (l & 15);
    int k0 = s * 32 + (l >> 4) * 8;
    const float* X = (row < N_HALF) ? src + (size_t)row * D
                                    : tgt + (size_t)(row - N_HALF) * D;
    float4 v0 = ((const float4*)(X + k0))[0];
    float4 v1 = ((const float4*)(X + k0))[1];
    float vs[8] = {v0.x, v0.y, v0.z, v0.w, v1.x, v1.y, v1.z, v1.w};
    half8 h;
    float p = 0.f;
#pragma unroll
    for (int e = 0; e < 8; ++e) {
        h[e] = (_Float16)vs[e];  // RNE
        p += vs[e] * vs[e];
    }
    ((half8*)Fh)[tid] = h;
    int w = t >> 6;
    // Column partials: reduce vs[e] over the 16 lanes sharing (l>>4) group.
    {
        float ce[8];
#pragma unroll
        for (int e = 0; e < 8; ++e) ce[e] = vs[e];
#pragma unroll
        for (int off = 1; off < 16; off <<= 1)
#pragma unroll
            for (int e = 0; e < 8; ++e) ce[e] += __shfl_xor(ce[e], off, 64);
        // lane l with l&15==0 holds the group's column sums for k0..k0+7
        if ((l & 15) == 0)
#pragma unroll
            for (int e = 0; e < 8; ++e) cs[w][k0 + e] = ce[e];
    }
    // Row norms: lanes l, l+16, l+32, l+48 share (row, s-half)
    p += __shfl_down(p, 32, 64);
    p += __shfl_down(p, 16, 64);
    if (l < 16) hn[w][l] = p;
    __syncthreads();
    if (t < 64) {
        float nr = 0.f;
        int tile = t >> 4, r = t & 15;
        if (t < 32) {
            nr = hn[tile * 2][r] + hn[tile * 2 + 1][r];
            g_norms[(blockIdx.x * 2 + tile) * 16 + r] = nr;
        }
        nr += __shfl_down(nr, 32, 64);
        nr += __shfl_down(nr, 16, 64);
        nr += __shfl_down(nr, 8, 64);
        nr += __shfl_down(nr, 4, 64);
        nr += __shfl_down(nr, 2, 64);
        nr += __shfl_down(nr, 1, 64);
        if (t == 0) g_pssq[blockIdx.x] = nr;
    }
    if (t < D) {
        // Columns 0-31 live in waves 0,2 (s=0); columns 32-63 in waves 1,3.
        float col = (t < 32) ? (cs[0][t] + cs[2][t]) : (cs[1][t] + cs[3][t]);
        g_pcol[blockIdx.x * D + t] = col;
    }
}

// Bandwidth coefficient, one small block.
__global__ __launch_bounds__(256) void mmd_bw() {
    __shared__ float scol[4][64];
    __shared__ float sssq[4];
    int t = threadIdx.x, w = t >> 6, l = t & 63;
    float csum = 0.f;
#pragma unroll 16
    for (int q = 0; q < 64; ++q) csum += g_pcol[(w * 64 + q) * 64 + l];
    float sq = g_pssq[w * 64 + l];
#pragma unroll
    for (int off = 32; off; off >>= 1) sq += __shfl_xor(sq, off, 64);
    scol[w][l] = csum;
    if (l == 0) sssq[w] = sq;
    __syncthreads();
    if (t < 64) {
        float colsum = (scol[0][l] + scol[1][l]) + (scol[2][l] + scol[3][l]);
        float s2 = colsum * colsum;
#pragma unroll
        for (int off = 32; off; off >>= 1) s2 += __shfl_xor(s2, off, 64);
        if (t == 0) {
            float ssq = (sssq[0] + sssq[1]) + (sssq[2] + sssq[3]);
            const float M = (float)M_TOT;
            float sumL2 = 2.f * M * ssq - 2.f * s2;
            float bwq = sumL2 / (M * M - M) * 0.25f;  // / KERNEL_MUL^2
            g_coef = -1.4426950408889634f / (bwq * 16.f);
        }
    }
}

static __device__ inline void decode_pair(int id, int& bi, int& bj) {
    bi = (int)(64.5f - sqrtf(4160.25f - 2.0f * (float)id));
    while ((64 * (bi + 1) - ((bi + 1) * bi) / 2) <= id) ++bi;
    while ((64 * bi - (bi * (bi - 1)) / 2) > id) --bi;
    bj = bi + (id - (64 * bi - (bi * (bi - 1)) / 2));
}

// Main: one 128x128 pair tile per block, 8 waves of 64x32 each (R11 base).
// XCD-chunked pair mapping: 2080 % 8 == 0 -> each XCD gets a contiguous
// run of 260 pair-ids (consecutive bi -> A-panel reuse in local L2).
__global__ __launch_bounds__(512) void mmd_main() {
    __shared__ float sred[8];
    int t = threadIdx.x, w = t >> 6, l = t & 63;
    int wr = w >> 2, wc = w & 3;  // 2x4 wave grid: 64 rows x 32 cols per wave
    float g0 = g_coef;
    float c2 = -2.f * g0;
    const half8* FH = (const half8*)Fh;

    int id = (blockIdx.x & 7) * 260 + (blockIdx.x >> 3);  // XCD-chunked (bijective)
    int bi, bj;
    decode_pair(id, bi, bj);

    // Norm loads issued early, pre-scaled by g0 (consumed in epilogue).
    float nas[4][4];
#pragma unroll
    for (int m = 0; m < 4; ++m) {
        float4 v = *(const float4*)&g_norms[bi * 128 + wr * 64 + m * 16 + (l >> 4) * 4];
        nas[m][0] = v.x * g0; nas[m][1] = v.y * g0;
        nas[m][2] = v.z * g0; nas[m][3] = v.w * g0;
    }
    float nbv[2];
#pragma unroll
    for (int n = 0; n < 2; ++n)
        nbv[n] = g_norms[bj * 128 + wc * 32 + n * 16 + (l & 15)] * g0;

    f32x4 acc[4][2] = {};
#pragma unroll
    for (int s = 0; s < 2; ++s) {
        half8 bh[2];
#pragma unroll
        for (int n = 0; n < 2; ++n)
            bh[n] = FH[((bj * 8 + wc * 2 + n) * 2 + s) * 64 + l];
#pragma unroll
        for (int m = 0; m < 4; ++m) {
            half8 ah = FH[((bi * 8 + wr * 4 + m) * 2 + s) * 64 + l];
#pragma unroll
            for (int n = 0; n < 2; ++n)
                acc[m][n] = __builtin_amdgcn_mfma_f32_16x16x32_f16(ah, bh[n], acc[m][n], 0, 0, 0);
        }
    }

    // Epilogue: K_sum over 5 bandwidths via 1 exp2 + 3 muls + fma-folded k0.
    float part4[4] = {0.f, 0.f, 0.f, 0.f};
#pragma unroll
    for (int m = 0; m < 4; ++m)
#pragma unroll
        for (int n = 0; n < 2; ++n)
#pragma unroll
            for (int r = 0; r < 4; ++r) {
                float t0 = fmaf(acc[m][n][r], c2, nas[m][r] + nbv[n]);
                float k4 = __builtin_amdgcn_exp2f(t0);
                float k3 = k4 * k4;
                float k2 = k3 * k3;
                float k1 = k2 * k2;
                float s5 = fmaf(k1, k1, (k4 + k3) + (k2 + k1));  // k0 folded
                part4[r] += s5;
            }
    float part = (part4[0] + part4[1]) + (part4[2] + part4[3]);

#pragma unroll
    for (int off = 32; off; off >>= 1) part += __shfl_down(part, off, 64);
    if (l == 0) sred[w] = part;
    __syncthreads();
    if (t == 0) {
        float tot = ((sred[0] + sred[1]) + (sred[2] + sred[3])) +
                    ((sred[4] + sred[5]) + (sred[6] + sred[7]));
        float sgn = ((bi < 32) == (bj < 32)) ? 1.f : -1.f;
        float scl = (bi == bj) ? 1.f : 2.f;
        g_part[id] = (double)tot * (double)(sgn * scl);
    }
}

// Deterministic tree reduce of the 2080 per-pair doubles.
__global__ __launch_bounds__(256) void mmd_out(float* __restrict__ out) {
    __shared__ double wred[4];
    int t = threadIdx.x;
    double s = 0.0;
    for (int i = t; i < NPAIR; i += 256) s += g_part[i];
#pragma unroll
    for (int off = 32; off; off >>= 1) s += __shfl_down(s, off, 64);
    if ((t & 63) == 0) wred[t >> 6] = s;
    __syncthreads();
    if (t == 0)
        out[0] = (float)((wred[0] + wred[1] + wred[2] + wred[3]) * (1.0 / 16777216.0));
}

extern "C" void kernel_launch(void* const* d_in, const int* in_sizes, int n_in,
                              void* d_out, int out_size, void* d_ws, size_t ws_size,
                              hipStream_t stream) {
    const float* src = (const float*)d_in[0];
    const float* tgt = (const float*)d_in[1];
    float* out = (float*)d_out;

    mmd_prep<<<256, 256, 0, stream>>>(src, tgt);
    mmd_bw<<<1, 256, 0, stream>>>();
    mmd_main<<<NPAIR, 512, 0, stream>>>();
    mmd_out<<<1, 256, 0, stream>>>(out);
}